// Round 5
// baseline (149.280 us; speedup 1.0000x reference)
//
#include <hip/hip_runtime.h>
#include <hip/hip_bf16.h>
#include <stdint.h>

typedef unsigned short u16t;

#define SDIM 224

__device__ __forceinline__ float lo16(uint32_t w) { union { uint32_t u; float f; } v; v.u = w << 16; return v.f; }
__device__ __forceinline__ float hi16(uint32_t w) { union { uint32_t u; float f; } v; v.u = w & 0xFFFF0000u; return v.f; }
__device__ __forceinline__ uint32_t f2bf(float f) {
    union { float f; uint32_t u; } v; v.f = f;
    return (v.u + 0x7FFFu + ((v.u >> 16) & 1u)) >> 16;
}

// ---------------------------------------------------------------------------
// Kernel A/B: hyperlinear embed (ally DIN=8 / enemy DIN=6), mean over 8 rows.
// emb[s,o] = ( sum_{h,i} Psum[s,h,i]*h2w[h,i*64+o] + sum_i xsum[s,i]*h2b[i*64+o] )/8 + bias[o]
// Psum[s,h,i] = sum_a relu(x_a @ h1w + h1b)[h] * x_a[i]
// f32 global I/O; h2w + Psum held as bf16 in LDS. Two K-passes for h2w.
// ---------------------------------------------------------------------------
template<int DIN>
__global__ __launch_bounds__(256, 2)
void hyper_embed_kernel(const float* __restrict__ states,
                        const float* __restrict__ h1w,   // [DIN][64]
                        const float* __restrict__ h1b,   // [64]
                        const float* __restrict__ h2w,   // [64][DIN*64]
                        const float* __restrict__ h2b,   // [DIN*64]
                        const float* __restrict__ bias,  // [64]
                        u16t* __restrict__ emb,          // [16384][64] bf16 scratch
                        int feat_off)
{
    constexpr int K  = DIN * 64;
    constexpr int KH = K / 2;          // columns staged per pass
    __shared__ __align__(16) u16t s_h2w[64 * KH];    // 32KB (ally) / 24KB (enemy)
    __shared__ __align__(16) u16t s_psum[K * 8];     // bf16 [K][8 samples]
    __shared__ __align__(16) float s_scr[2048];      // f32 [256 threads][8]
    __shared__ float s_h1w[DIN * 64];
    __shared__ float s_h1b[64];
    __shared__ float s_h2b[K];
    __shared__ float s_bias[64];
    __shared__ float s_xsum[8][DIN];

    const int tid = threadIdx.x;
    const float4* h2w_v = (const float4*)h2w;        // [64][K/4]

    // ---- load small weights + h2w pass 0 (f32 -> bf16) ----
    {
        for (int idx = tid; idx < 64 * (KH / 4); idx += 256) {
            int h = idx / (KH / 4), c = idx - h * (KH / 4);
            float4 v = h2w_v[h * (K / 4) + c];       // pass 0: cols [0, KH)
            uint2 pk2;
            pk2.x = f2bf(v.x) | (f2bf(v.y) << 16);
            pk2.y = f2bf(v.z) | (f2bf(v.w) << 16);
            *(uint2*)&s_h2w[h * KH + c * 4] = pk2;
        }
        for (int idx = tid; idx < DIN * 64; idx += 256) s_h1w[idx] = h1w[idx];
        for (int idx = tid; idx < K; idx += 256) s_h2b[idx] = h2b[idx];
        if (tid < 64) { s_h1b[tid] = h1b[tid]; s_bias[tid] = bias[tid]; }
    }
    __syncthreads();   // stage 1 reads s_h1w/s_h1b written by other waves

    // ---- stage 1: per-sample Psum (lane = h), transposed into LDS ----
    {
        const int wave = tid >> 6;
        const int lane = tid & 63;
        for (int ss = 0; ss < 2; ++ss) {
            const int s = wave * 2 + ss;
            const int r = blockIdx.x * 8 + s;
            const float* xrow = states + (size_t)r * SDIM + feat_off;
            float ps[DIN], xs[DIN];
#pragma unroll
            for (int i = 0; i < DIN; ++i) { ps[i] = 0.f; xs[i] = 0.f; }
#pragma unroll
            for (int a = 0; a < 8; ++a) {
                float x[DIN];
#pragma unroll
                for (int i = 0; i < DIN; ++i) x[i] = xrow[a * DIN + i];
                float hacc = s_h1b[lane];
#pragma unroll
                for (int i = 0; i < DIN; ++i) hacc += x[i] * s_h1w[i * 64 + lane];
                hacc = fmaxf(hacc, 0.f);
#pragma unroll
                for (int i = 0; i < DIN; ++i) { ps[i] += hacc * x[i]; xs[i] += x[i]; }
            }
            // transposed psum: row kk = i*64 + h, col s
#pragma unroll
            for (int i = 0; i < DIN; ++i) s_psum[(i * 64 + lane) * 8 + s] = (u16t)f2bf(ps[i]);
            if (lane == 0) {
#pragma unroll
                for (int i = 0; i < DIN; ++i) s_xsum[s][i] = xs[i];
            }
        }
    }
    __syncthreads();

    // ---- stage 2: contraction over K in two passes ----
    const int oq = tid & 31;          // o-pair
    const int sh = (tid >> 5) & 1;    // sample half
    const int kh = tid >> 6;          // K quarter (= wave)
    const int o0 = oq * 2;
    constexpr int KQ = KH / 4;        // iterations per thread per pass

    float acc00 = 0, acc01 = 0, acc02 = 0, acc03 = 0;
    float acc10 = 0, acc11 = 0, acc12 = 0, acc13 = 0;

#pragma unroll 1
    for (int p = 0; p < 2; ++p) {
        if (p == 1) {
            __syncthreads();          // all threads done reading pass-0 h2w
            for (int idx = tid; idx < 64 * (KH / 4); idx += 256) {
                int h = idx / (KH / 4), c = idx - h * (KH / 4);
                float4 v = h2w_v[h * (K / 4) + (KH / 4) + c];   // pass 1: cols [KH, K)
                uint2 pk2;
                pk2.x = f2bf(v.x) | (f2bf(v.y) << 16);
                pk2.y = f2bf(v.z) | (f2bf(v.w) << 16);
                *(uint2*)&s_h2w[h * KH + c * 4] = pk2;
            }
            __syncthreads();
        }
        int kk = kh * KQ;             // local col index within this pass
        int i_l = kk >> 6;
        int h = kk & 63;
        const u16t* psb = s_psum + ((size_t)(p * KH) + kk) * 8 + sh * 4;
#pragma unroll 4
        for (int n = 0; n < KQ; ++n) {
            uint32_t wv = *(const uint32_t*)&s_h2w[(h * (DIN / 2) + i_l) * 64 + o0];
            uint2 pv = *(const uint2*)psb;
            float w0 = lo16(wv), w1 = hi16(wv);
            float p0 = lo16(pv.x), p1 = hi16(pv.x), p2 = lo16(pv.y), p3 = hi16(pv.y);
            acc00 += w0 * p0; acc01 += w0 * p1; acc02 += w0 * p2; acc03 += w0 * p3;
            acc10 += w1 * p0; acc11 += w1 * p1; acc12 += w1 * p2; acc13 += w1 * p3;
            psb += 8;
            ++h;
            if (h == 64) { h = 0; ++i_l; }
        }
    }

    // ---- reduction across K-quarters + epilogue ----
    s_scr[tid * 8 + 0] = acc00; s_scr[tid * 8 + 1] = acc01;
    s_scr[tid * 8 + 2] = acc02; s_scr[tid * 8 + 3] = acc03;
    s_scr[tid * 8 + 4] = acc10; s_scr[tid * 8 + 5] = acc11;
    s_scr[tid * 8 + 6] = acc12; s_scr[tid * 8 + 7] = acc13;
    __syncthreads();

    const int u0 = tid * 2;
    const int s = u0 >> 6;
    const int o = u0 & 63;
    float res[2];
#pragma unroll
    for (int uu = 0; uu < 2; ++uu) {
        const int oo = o + uu;
        const int base = ((oo >> 1) + ((s >> 2) << 5)) * 8 + (oo & 1) * 4 + (s & 3);
        float v = 0.f;
#pragma unroll
        for (int k4 = 0; k4 < 4; ++k4) v += s_scr[base + k4 * 512];
        float hb = 0.f;
#pragma unroll
        for (int i2 = 0; i2 < DIN; ++i2) hb += s_xsum[s][i2] * s_h2b[i2 * 64 + oo];
        res[uu] = (v + hb) * 0.125f + s_bias[oo];
    }
    uint32_t pk = f2bf(res[0]) | (f2bf(res[1]) << 16);
    *(uint32_t*)&emb[((size_t)(blockIdx.x * 8 + s)) * 64 + o] = pk;
}

// ---------------------------------------------------------------------------
// Kernel C: action embed + se + w1 softmax + b1/w2/b2 + final mix. Wave/sample.
// ---------------------------------------------------------------------------
__global__ __launch_bounds__(256, 2)
void final_kernel(const float* __restrict__ qvals, const float* __restrict__ states,
                  const float* __restrict__ hs,
                  const u16t* __restrict__ embA, const u16t* __restrict__ embB,
                  const float* __restrict__ hw1_w, const float* __restrict__ hw1_b,
                  const float* __restrict__ act_w, const float* __restrict__ act_b,
                  const float* __restrict__ hb1_w, const float* __restrict__ hb1_b,
                  const float* __restrict__ hw2_w, const float* __restrict__ hw2_b,
                  const float* __restrict__ hb2_w, const float* __restrict__ hb2_b,
                  float* __restrict__ out)
{
    __shared__ float s_hw1w[64 * 32];
    __shared__ float s_hb1w[64 * 32];
    __shared__ float s_hw2w[64 * 32];
    __shared__ float s_actw[14 * 64];
    __shared__ float s_hw1b[32], s_hb1b[32], s_hw2b[32], s_actb[64], s_hb2wv[64];
    __shared__ float s_hb2b;
    __shared__ __align__(16) float s_hsf[4][512];
    __shared__ float s_se[4][64];
    __shared__ float s_am[4][14];

    const int tid = threadIdx.x;
    for (int idx = tid; idx < 2048; idx += 256) {
        s_hw1w[idx] = hw1_w[idx];
        s_hb1w[idx] = hb1_w[idx];
        s_hw2w[idx] = hw2_w[idx];
    }
    for (int idx = tid; idx < 896; idx += 256) s_actw[idx] = act_w[idx];
    if (tid < 32) { s_hw1b[tid] = hw1_b[tid]; s_hb1b[tid] = hb1_b[tid]; s_hw2b[tid] = hw2_b[tid]; }
    if (tid >= 64 && tid < 128) s_actb[tid - 64] = act_b[tid - 64];
    if (tid >= 128 && tid < 192) s_hb2wv[tid - 128] = hb2_w[tid - 128];
    if (tid == 255) s_hb2b = hb2_b[0];

    const int w = tid >> 6, lane = tid & 63;
    const int r = blockIdx.x * 4 + w;

    // hidden_states -> f32 LDS
    {
        const float4* hp4 = (const float4*)(hs + (size_t)r * 512);
        *(float4*)&s_hsf[w][lane * 8]     = hp4[lane * 2];
        *(float4*)&s_hsf[w][lane * 8 + 4] = hp4[lane * 2 + 1];
    }
    // action means
    if (lane < 14) {
        const float* ap = states + (size_t)r * SDIM + 112 + lane;
        float am = 0.f;
#pragma unroll
        for (int a = 0; a < 8; ++a) am += ap[a * 14];
        s_am[w][lane] = am * 0.125f;
    }
    __syncthreads();

    // se (lane = o)
    {
        float ea = lo16((uint32_t)embA[(size_t)r * 64 + lane]);   // bf16 -> f32 (lo16 does the <<16)
        float eb = lo16((uint32_t)embB[(size_t)r * 64 + lane]);
        float eact = s_actb[lane];
#pragma unroll
        for (int j = 0; j < 14; ++j) eact += s_am[w][j] * s_actw[j * 64 + lane];
        s_se[w][lane] = fmaxf(ea + eb + eact, 0.f);
    }
    __syncthreads();

    const int e = lane & 31, ah = lane >> 5;

    // w1 pre-softmax: z[a=ah+2j][e]
    float z0, z1, z2, z3;
    z0 = z1 = z2 = z3 = s_hw1b[e];
    {
        const float* h0p = &s_hsf[w][(ah + 0) * 64];
        const float* h1p = &s_hsf[w][(ah + 2) * 64];
        const float* h2p = &s_hsf[w][(ah + 4) * 64];
        const float* h3p = &s_hsf[w][(ah + 6) * 64];
        for (int k4 = 0; k4 < 16; ++k4) {
            float4 a0 = *(const float4*)&h0p[k4 * 4];
            float4 a1 = *(const float4*)&h1p[k4 * 4];
            float4 a2 = *(const float4*)&h2p[k4 * 4];
            float4 a3 = *(const float4*)&h3p[k4 * 4];
#define ZSTEP(kk, comp) { float wv = s_hw1w[(k4 * 4 + kk) * 32 + e]; \
            z0 += a0.comp * wv; z1 += a1.comp * wv; z2 += a2.comp * wv; z3 += a3.comp * wv; }
            ZSTEP(0, x) ZSTEP(1, y) ZSTEP(2, z) ZSTEP(3, w)
#undef ZSTEP
        }
    }
    // softmax over 8 agents (pair lanes e <-> e+32)
    float m = fmaxf(fmaxf(z0, z1), fmaxf(z2, z3));
    m = fmaxf(m, __shfl_xor(m, 32));
    float x0 = __expf(z0 - m), x1 = __expf(z1 - m), x2 = __expf(z2 - m), x3 = __expf(z3 - m);
    float ssum = x0 + x1 + x2 + x3;
    ssum += __shfl_xor(ssum, 32);
    float inv = 1.0f / ssum;

    // b1 (lanes<32) / w2 (lanes>=32)
    float bw;
    {
        const float* mat = (lane < 32) ? s_hb1w : s_hw2w;
        bw = (lane < 32) ? s_hb1b[e] : s_hw2b[e];
#pragma unroll 8
        for (int o = 0; o < 64; ++o) bw += s_se[w][o] * mat[o * 32 + e];
        if (lane >= 32) bw = fabsf(bw);
    }
    // b2
    float p2 = s_se[w][lane] * s_hb2wv[lane];
#pragma unroll
    for (int m2 = 1; m2 < 64; m2 <<= 1) p2 += __shfl_xor(p2, m2);
    float b2 = p2 + s_hb2b;

    // hidden = elu(q @ w1 + b1); y = hidden @ w2 + b2
    float qa0, qa1, qa2, qa3;
    {
        const float* qp = qvals + (size_t)r * 8 + ah;
        qa0 = qp[0]; qa1 = qp[2]; qa2 = qp[4]; qa3 = qp[6];
    }
    float hp = qa0 * (x0 * inv) + qa1 * (x1 * inv) + qa2 * (x2 * inv) + qa3 * (x3 * inv);
    hp += __shfl_xor(hp, 32);
    float hval = hp + bw;                       // lanes<32: + b1[e]
    float hd = (hval > 0.f) ? hval : (__expf(hval) - 1.f);
    float w2v = __shfl(bw, (lane & 31) + 32);   // w2[e]
    float yp = hd * w2v;
#pragma unroll
    for (int m2 = 1; m2 < 32; m2 <<= 1) yp += __shfl_xor(yp, m2);
    if (lane == 0) out[r] = yp + b2;
}

extern "C" void kernel_launch(void* const* d_in, const int* in_sizes, int n_in,
                              void* d_out, int out_size, void* d_ws, size_t ws_size,
                              hipStream_t stream) {
    const float* qvals   = (const float*)d_in[0];
    const float* states  = (const float*)d_in[1];
    const float* hstates = (const float*)d_in[2];
    const float* hw1_w   = (const float*)d_in[3];
    const float* hw1_b   = (const float*)d_in[4];
    const float* en_h1w  = (const float*)d_in[5];
    const float* en_h1b  = (const float*)d_in[6];
    const float* en_h2w  = (const float*)d_in[7];
    const float* en_h2b  = (const float*)d_in[8];
    const float* en_bias = (const float*)d_in[9];
    const float* al_h1w  = (const float*)d_in[10];
    const float* al_h1b  = (const float*)d_in[11];
    const float* al_h2w  = (const float*)d_in[12];
    const float* al_h2b  = (const float*)d_in[13];
    const float* al_bias = (const float*)d_in[14];
    const float* act_w   = (const float*)d_in[15];
    const float* act_b   = (const float*)d_in[16];
    const float* hb1_w   = (const float*)d_in[17];
    const float* hb1_b   = (const float*)d_in[18];
    const float* hw2_w   = (const float*)d_in[19];
    const float* hw2_b   = (const float*)d_in[20];
    const float* hb2_w   = (const float*)d_in[21];
    const float* hb2_b   = (const float*)d_in[22];

    u16t* embA = (u16t*)d_ws;
    u16t* embB = embA + (size_t)16384 * 64;

    hyper_embed_kernel<8><<<2048, 256, 0, stream>>>(states, al_h1w, al_h1b, al_h2w, al_h2b, al_bias, embA, 0);
    hyper_embed_kernel<6><<<2048, 256, 0, stream>>>(states, en_h1w, en_h1b, en_h2w, en_h2b, en_bias, embB, 64);
    final_kernel<<<4096, 256, 0, stream>>>(qvals, states, hstates, embA, embB,
                                           hw1_w, hw1_b, act_w, act_b, hb1_w, hb1_b,
                                           hw2_w, hw2_b, hb2_w, hb2_b, (float*)d_out);
}

// Round 6
// 64.356 us; speedup vs baseline: 2.3196x; 2.3196x over previous
//
#include <hip/hip_runtime.h>
#include <hip/hip_bf16.h>
#include <stdint.h>

typedef unsigned short u16t;
typedef float f32x4 __attribute__((ext_vector_type(4)));
typedef short bf16x8 __attribute__((ext_vector_type(8)));

#define SDIM 224

__device__ __forceinline__ float lo16(uint32_t w) { union { uint32_t u; float f; } v; v.u = w << 16; return v.f; }
__device__ __forceinline__ float hi16(uint32_t w) { union { uint32_t u; float f; } v; v.u = w & 0xFFFF0000u; return v.f; }
__device__ __forceinline__ uint32_t f2bf(float f) {
    union { float f; uint32_t u; } v; v.f = f;
    return (v.u + 0x7FFFu + ((v.u >> 16) & 1u)) >> 16;
}

// ---------------------------------------------------------------------------
// Prep: pack h2w (f32 [64][DIN*64]) into MFMA-B-fragment-ordered bf16:
// Wt[(kb*64 + n)*8 + j] = bf16(h2w[h][i*64+n]), k = kb*8+j, h = k&63, i = k>>6
// (k-index = i*64 + h matches the Psum LDS layout in the fused kernel.)
// ---------------------------------------------------------------------------
__global__ void prep_wt_kernel(const float* __restrict__ h2wA, const float* __restrict__ h2wB,
                               u16t* __restrict__ wtA, u16t* __restrict__ wtB)
{
    for (int e = blockIdx.x * 256 + threadIdx.x; e < 32768; e += gridDim.x * 256) {
        int j = e & 7, n = (e >> 3) & 63, kb = e >> 9;
        int k = kb * 8 + j, h = k & 63, i = k >> 6;
        wtA[e] = (u16t)f2bf(h2wA[h * 512 + i * 64 + n]);
    }
    for (int e = blockIdx.x * 256 + threadIdx.x; e < 24576; e += gridDim.x * 256) {
        int j = e & 7, n = (e >> 3) & 63, kb = e >> 9;
        int k = kb * 8 + j, h = k & 63, i = k >> 6;
        wtB[e] = (u16t)f2bf(h2wB[h * 384 + i * 64 + n]);
    }
}

// ---------------------------------------------------------------------------
// Fused hyper-embed: stage 1 (VALU) builds Psum[s][k=i*64+h] bf16 in LDS,
// stage 2 contracts with Wt via mfma_f32_16x16x32_bf16. 32 samples/block.
// emb[s,o] = (Psum[s,:]·Wt[:,o] + xsum[s,:]·h2b[:,o]) / 8 + bias[o]
// ---------------------------------------------------------------------------
template<int DIN>
__global__ __launch_bounds__(256, 4)
void hyper_embed_mfma(const float* __restrict__ states,
                      const float* __restrict__ h1w,   // [DIN][64]
                      const float* __restrict__ h1b,   // [64]
                      const u16t*  __restrict__ wt,    // packed B fragments
                      const float* __restrict__ h2b,   // [DIN*64]
                      const float* __restrict__ bias,  // [64]
                      u16t* __restrict__ emb,          // [16384][64] bf16
                      int feat_off)
{
    constexpr int K  = DIN * 64;
    constexpr int KP = K + 8;                     // row pad: stride 1040B/784B -> 2-way banks
    __shared__ __align__(16) u16t  s_psum[32 * KP];
    __shared__ __align__(16) float s_x[32][DIN * 8];
    __shared__ float s_h1w[DIN * 64];
    __shared__ float s_h2b[DIN * 64];
    __shared__ float s_h1b[64];
    __shared__ float s_bias[64];
    __shared__ float s_xsum[32][DIN];

    const int tid  = threadIdx.x;
    const int wave = tid >> 6;
    const int lane = tid & 63;

    // ---- cooperative loads ----
    for (int idx = tid; idx < DIN * 64; idx += 256) { s_h1w[idx] = h1w[idx]; s_h2b[idx] = h2b[idx]; }
    if (tid < 64) { s_h1b[tid] = h1b[tid]; s_bias[tid] = bias[tid]; }
    {
        constexpr int V4 = DIN * 2;               // float4s per sample
        for (int idx = tid; idx < 32 * V4; idx += 256) {
            int s = idx / V4, c = idx - s * V4;
            *(float4*)&s_x[s][c * 4] =
                *(const float4*)(states + (size_t)(blockIdx.x * 32 + s) * SDIM + feat_off + c * 4);
        }
    }
    __syncthreads();

    // ---- stage 1: Psum (lane = h), 8 samples per wave ----
    {
        float w1r[DIN];
#pragma unroll
        for (int i = 0; i < DIN; ++i) w1r[i] = s_h1w[i * 64 + lane];
        const float b1r = s_h1b[lane];

        for (int ss = 0; ss < 8; ++ss) {
            const int s = wave * 8 + ss;
            float ps[DIN], xs[DIN];
#pragma unroll
            for (int i = 0; i < DIN; ++i) { ps[i] = 0.f; xs[i] = 0.f; }
#pragma unroll
            for (int a = 0; a < 8; ++a) {
                float x[DIN];
                if constexpr (DIN == 8) {
                    float4 v0 = *(const float4*)&s_x[s][a * 8];
                    float4 v1 = *(const float4*)&s_x[s][a * 8 + 4];
                    x[0] = v0.x; x[1] = v0.y; x[2] = v0.z; x[3] = v0.w;
                    x[4] = v1.x; x[5] = v1.y; x[6] = v1.z; x[7] = v1.w;
                } else {
                    float2 v0 = *(const float2*)&s_x[s][a * 6];
                    float2 v1 = *(const float2*)&s_x[s][a * 6 + 2];
                    float2 v2 = *(const float2*)&s_x[s][a * 6 + 4];
                    x[0] = v0.x; x[1] = v0.y; x[2] = v1.x; x[3] = v1.y; x[4] = v2.x; x[5] = v2.y;
                }
                float hacc = b1r;
#pragma unroll
                for (int i = 0; i < DIN; ++i) hacc += x[i] * w1r[i];
                hacc = fmaxf(hacc, 0.f);
#pragma unroll
                for (int i = 0; i < DIN; ++i) { ps[i] += hacc * x[i]; xs[i] += x[i]; }
            }
#pragma unroll
            for (int i = 0; i < DIN; ++i) s_psum[s * KP + i * 64 + lane] = (u16t)f2bf(ps[i]);
            if (lane == 0) {
#pragma unroll
                for (int i = 0; i < DIN; ++i) s_xsum[s][i] = xs[i];
            }
        }
    }
    __syncthreads();

    // ---- stage 2: MFMA GEMM. wave -> (wm = sample-half, wn = n-half) ----
    const int wm = wave & 1, wn = wave >> 1;
    const int smp0 = wm * 16;
    const int n0 = wn * 32;
    const int lr = lane & 15, lg = lane >> 4;

    f32x4 acc0 = {0.f, 0.f, 0.f, 0.f};
    f32x4 acc1 = {0.f, 0.f, 0.f, 0.f};
    const u16t* arow = &s_psum[(smp0 + lr) * KP + lg * 8];
    const bf16x8* wt8 = (const bf16x8*)wt;

#pragma unroll 4
    for (int kk = 0; kk < K; kk += 32) {
        bf16x8 av = *(const bf16x8*)(arow + kk);
        bf16x8 b0 = wt8[((kk >> 3) + lg) * 64 + n0 + lr];
        bf16x8 b1 = wt8[((kk >> 3) + lg) * 64 + n0 + 16 + lr];
        acc0 = __builtin_amdgcn_mfma_f32_16x16x32_bf16(av, b0, acc0, 0, 0, 0);
        acc1 = __builtin_amdgcn_mfma_f32_16x16x32_bf16(av, b1, acc1, 0, 0, 0);
    }

    // ---- epilogue: + xsum·h2b, /8, + bias; D layout: col=lane&15, row=4*(lane>>4)+j ----
#pragma unroll
    for (int f = 0; f < 2; ++f) {
        f32x4 acc = f ? acc1 : acc0;
        const int o = n0 + f * 16 + lr;
#pragma unroll
        for (int j = 0; j < 4; ++j) {
            const int srow = smp0 + lg * 4 + j;
            float hb = 0.f;
#pragma unroll
            for (int i = 0; i < DIN; ++i) hb += s_xsum[srow][i] * s_h2b[i * 64 + o];
            float res = (acc[j] + hb) * 0.125f + s_bias[o];
            emb[(size_t)(blockIdx.x * 32 + srow) * 64 + o] = (u16t)f2bf(res);
        }
    }
}

// ---------------------------------------------------------------------------
// Kernel C: action embed + se + w1 softmax + b1/w2/b2 + final mix. Wave/sample.
// ---------------------------------------------------------------------------
__global__ __launch_bounds__(256, 2)
void final_kernel(const float* __restrict__ qvals, const float* __restrict__ states,
                  const float* __restrict__ hs,
                  const u16t* __restrict__ embA, const u16t* __restrict__ embB,
                  const float* __restrict__ hw1_w, const float* __restrict__ hw1_b,
                  const float* __restrict__ act_w, const float* __restrict__ act_b,
                  const float* __restrict__ hb1_w, const float* __restrict__ hb1_b,
                  const float* __restrict__ hw2_w, const float* __restrict__ hw2_b,
                  const float* __restrict__ hb2_w, const float* __restrict__ hb2_b,
                  float* __restrict__ out)
{
    __shared__ float s_hw1w[64 * 32];
    __shared__ float s_hb1w[64 * 32];
    __shared__ float s_hw2w[64 * 32];
    __shared__ float s_actw[14 * 64];
    __shared__ float s_hw1b[32], s_hb1b[32], s_hw2b[32], s_actb[64], s_hb2wv[64];
    __shared__ float s_hb2b;
    __shared__ __align__(16) float s_hsf[4][512];
    __shared__ float s_se[4][64];
    __shared__ float s_am[4][14];

    const int tid = threadIdx.x;
    for (int idx = tid; idx < 2048; idx += 256) {
        s_hw1w[idx] = hw1_w[idx];
        s_hb1w[idx] = hb1_w[idx];
        s_hw2w[idx] = hw2_w[idx];
    }
    for (int idx = tid; idx < 896; idx += 256) s_actw[idx] = act_w[idx];
    if (tid < 32) { s_hw1b[tid] = hw1_b[tid]; s_hb1b[tid] = hb1_b[tid]; s_hw2b[tid] = hw2_b[tid]; }
    if (tid >= 64 && tid < 128) s_actb[tid - 64] = act_b[tid - 64];
    if (tid >= 128 && tid < 192) s_hb2wv[tid - 128] = hb2_w[tid - 128];
    if (tid == 255) s_hb2b = hb2_b[0];

    const int w = tid >> 6, lane = tid & 63;
    const int r = blockIdx.x * 4 + w;

    // hidden_states -> f32 LDS
    {
        const float4* hp4 = (const float4*)(hs + (size_t)r * 512);
        *(float4*)&s_hsf[w][lane * 8]     = hp4[lane * 2];
        *(float4*)&s_hsf[w][lane * 8 + 4] = hp4[lane * 2 + 1];
    }
    // action means
    if (lane < 14) {
        const float* ap = states + (size_t)r * SDIM + 112 + lane;
        float am = 0.f;
#pragma unroll
        for (int a = 0; a < 8; ++a) am += ap[a * 14];
        s_am[w][lane] = am * 0.125f;
    }
    __syncthreads();

    // se (lane = o)
    {
        float ea = lo16((uint32_t)embA[(size_t)r * 64 + lane]);
        float eb = lo16((uint32_t)embB[(size_t)r * 64 + lane]);
        float eact = s_actb[lane];
#pragma unroll
        for (int j = 0; j < 14; ++j) eact += s_am[w][j] * s_actw[j * 64 + lane];
        s_se[w][lane] = fmaxf(ea + eb + eact, 0.f);
    }
    __syncthreads();

    const int e = lane & 31, ah = lane >> 5;

    // w1 pre-softmax: z[a=ah+2j][e]
    float z0, z1, z2, z3;
    z0 = z1 = z2 = z3 = s_hw1b[e];
    {
        const float* h0p = &s_hsf[w][(ah + 0) * 64];
        const float* h1p = &s_hsf[w][(ah + 2) * 64];
        const float* h2p = &s_hsf[w][(ah + 4) * 64];
        const float* h3p = &s_hsf[w][(ah + 6) * 64];
        for (int k4 = 0; k4 < 16; ++k4) {
            float4 a0 = *(const float4*)&h0p[k4 * 4];
            float4 a1 = *(const float4*)&h1p[k4 * 4];
            float4 a2 = *(const float4*)&h2p[k4 * 4];
            float4 a3 = *(const float4*)&h3p[k4 * 4];
#define ZSTEP(kk, comp) { float wv = s_hw1w[(k4 * 4 + kk) * 32 + e]; \
            z0 += a0.comp * wv; z1 += a1.comp * wv; z2 += a2.comp * wv; z3 += a3.comp * wv; }
            ZSTEP(0, x) ZSTEP(1, y) ZSTEP(2, z) ZSTEP(3, w)
#undef ZSTEP
        }
    }
    // softmax over 8 agents (pair lanes e <-> e+32)
    float m = fmaxf(fmaxf(z0, z1), fmaxf(z2, z3));
    m = fmaxf(m, __shfl_xor(m, 32));
    float x0 = __expf(z0 - m), x1 = __expf(z1 - m), x2 = __expf(z2 - m), x3 = __expf(z3 - m);
    float ssum = x0 + x1 + x2 + x3;
    ssum += __shfl_xor(ssum, 32);
    float inv = 1.0f / ssum;

    // b1 (lanes<32) / w2 (lanes>=32)
    float bw;
    {
        const float* mat = (lane < 32) ? s_hb1w : s_hw2w;
        bw = (lane < 32) ? s_hb1b[e] : s_hw2b[e];
#pragma unroll 8
        for (int o = 0; o < 64; ++o) bw += s_se[w][o] * mat[o * 32 + e];
        if (lane >= 32) bw = fabsf(bw);
    }
    // b2
    float p2 = s_se[w][lane] * s_hb2wv[lane];
#pragma unroll
    for (int m2 = 1; m2 < 64; m2 <<= 1) p2 += __shfl_xor(p2, m2);
    float b2 = p2 + s_hb2b;

    // hidden = elu(q @ w1 + b1); y = hidden @ w2 + b2
    float qa0, qa1, qa2, qa3;
    {
        const float* qp = qvals + (size_t)r * 8 + ah;
        qa0 = qp[0]; qa1 = qp[2]; qa2 = qp[4]; qa3 = qp[6];
    }
    float hp = qa0 * (x0 * inv) + qa1 * (x1 * inv) + qa2 * (x2 * inv) + qa3 * (x3 * inv);
    hp += __shfl_xor(hp, 32);
    float hval = hp + bw;                       // lanes<32: + b1[e]
    float hd = (hval > 0.f) ? hval : (__expf(hval) - 1.f);
    float w2v = __shfl(bw, (lane & 31) + 32);   // w2[e]
    float yp = hd * w2v;
#pragma unroll
    for (int m2 = 1; m2 < 32; m2 <<= 1) yp += __shfl_xor(yp, m2);
    if (lane == 0) out[r] = yp + b2;
}

extern "C" void kernel_launch(void* const* d_in, const int* in_sizes, int n_in,
                              void* d_out, int out_size, void* d_ws, size_t ws_size,
                              hipStream_t stream) {
    const float* qvals   = (const float*)d_in[0];
    const float* states  = (const float*)d_in[1];
    const float* hstates = (const float*)d_in[2];
    const float* hw1_w   = (const float*)d_in[3];
    const float* hw1_b   = (const float*)d_in[4];
    const float* en_h1w  = (const float*)d_in[5];
    const float* en_h1b  = (const float*)d_in[6];
    const float* en_h2w  = (const float*)d_in[7];
    const float* en_h2b  = (const float*)d_in[8];
    const float* en_bias = (const float*)d_in[9];
    const float* al_h1w  = (const float*)d_in[10];
    const float* al_h1b  = (const float*)d_in[11];
    const float* al_h2w  = (const float*)d_in[12];
    const float* al_h2b  = (const float*)d_in[13];
    const float* al_bias = (const float*)d_in[14];
    const float* act_w   = (const float*)d_in[15];
    const float* act_b   = (const float*)d_in[16];
    const float* hb1_w   = (const float*)d_in[17];
    const float* hb1_b   = (const float*)d_in[18];
    const float* hw2_w   = (const float*)d_in[19];
    const float* hw2_b   = (const float*)d_in[20];
    const float* hb2_w   = (const float*)d_in[21];
    const float* hb2_b   = (const float*)d_in[22];

    // d_ws layout (u16 units): wtA[32768] | wtB[24576 -> @32768] | embA @65536 | embB @65536+1048576
    u16t* wtA  = (u16t*)d_ws;
    u16t* wtB  = wtA + 32768;
    u16t* embA = wtA + 65536;
    u16t* embB = embA + (size_t)16384 * 64;

    prep_wt_kernel<<<64, 256, 0, stream>>>(al_h2w, en_h2w, wtA, wtB);
    hyper_embed_mfma<8><<<512, 256, 0, stream>>>(states, al_h1w, al_h1b, wtA, al_h2b, al_bias, embA, 0);
    hyper_embed_mfma<6><<<512, 256, 0, stream>>>(states, en_h1w, en_h1b, wtB, en_h2b, en_bias, embB, 64);
    final_kernel<<<4096, 256, 0, stream>>>(qvals, states, hstates, embA, embB,
                                           hw1_w, hw1_b, act_w, act_b, hb1_w, hb1_b,
                                           hw2_w, hw2_b, hb2_w, hb2_b, (float*)d_out);
}

// Round 7
// 54.297 us; speedup vs baseline: 2.7493x; 1.1853x over previous
//
#include <hip/hip_runtime.h>
#include <hip/hip_bf16.h>
#include <stdint.h>

typedef unsigned short u16t;
typedef float f32x4 __attribute__((ext_vector_type(4)));
typedef short bf16x8 __attribute__((ext_vector_type(8)));

#define SDIM 224

__device__ __forceinline__ float lo16(uint32_t w) { union { uint32_t u; float f; } v; v.u = w << 16; return v.f; }
__device__ __forceinline__ uint32_t f2bf(float f) {
    union { float f; uint32_t u; } v; v.f = f;
    return (v.u + 0x7FFFu + ((v.u >> 16) & 1u)) >> 16;
}

// ---------------------------------------------------------------------------
// Prep: pack h2w (f32 [64][DIN*64]) into MFMA-B-fragment-ordered bf16:
// Wt[(kb*64 + n)*8 + j] = bf16(h2w[h][i*64+n]), k = kb*8+j, h = k&63, i = k>>6
// ---------------------------------------------------------------------------
__global__ void prep_wt_kernel(const float* __restrict__ h2wA, const float* __restrict__ h2wB,
                               u16t* __restrict__ wtA, u16t* __restrict__ wtB)
{
    for (int e = blockIdx.x * 256 + threadIdx.x; e < 32768; e += gridDim.x * 256) {
        int j = e & 7, n = (e >> 3) & 63, kb = e >> 9;
        int k = kb * 8 + j, h = k & 63, i = k >> 6;
        wtA[e] = (u16t)f2bf(h2wA[h * 512 + i * 64 + n]);
    }
    for (int e = blockIdx.x * 256 + threadIdx.x; e < 24576; e += gridDim.x * 256) {
        int j = e & 7, n = (e >> 3) & 63, kb = e >> 9;
        int k = kb * 8 + j, h = k & 63, i = k >> 6;
        wtB[e] = (u16t)f2bf(h2wB[h * 384 + i * 64 + n]);
    }
}

// ---------------------------------------------------------------------------
// A/B: fused hyper-embed. 16 samples/block, grid 1024.
// stage1 (VALU): Psum[s][k=i*64+h] bf16 in LDS; stage2: 16x16x32 MFMA vs Wt.
// ---------------------------------------------------------------------------
template<int DIN>
__global__ __launch_bounds__(256, 4)
void hyper_embed_mfma(const float* __restrict__ states,
                      const float* __restrict__ h1w,   // [DIN][64]
                      const float* __restrict__ h1b,   // [64]
                      const u16t*  __restrict__ wt,    // packed B fragments
                      const float* __restrict__ h2b,   // [DIN*64]
                      const float* __restrict__ bias,  // [64]
                      u16t* __restrict__ emb,          // [16384][64] bf16
                      int feat_off)
{
    constexpr int K  = DIN * 64;
    constexpr int KP = K + 8;                     // pad: 1040B/784B stride -> 2-way banks
    __shared__ __align__(16) u16t  s_psum[16 * KP];
    __shared__ __align__(16) float s_x[16][DIN * 8];
    __shared__ float s_h1w[DIN * 64];
    __shared__ float s_h2b[DIN * 64];
    __shared__ float s_h1b[64];
    __shared__ float s_bias[64];
    __shared__ float s_xsum[16][DIN];

    const int tid  = threadIdx.x;
    const int wave = tid >> 6;
    const int lane = tid & 63;
    const int sbase = blockIdx.x * 16;

    for (int idx = tid; idx < DIN * 64; idx += 256) { s_h1w[idx] = h1w[idx]; s_h2b[idx] = h2b[idx]; }
    if (tid < 64) { s_h1b[tid] = h1b[tid]; s_bias[tid] = bias[tid]; }
    {
        constexpr int V4 = DIN * 2;               // float4s per sample
        for (int idx = tid; idx < 16 * V4; idx += 256) {
            int s = idx / V4, c = idx - s * V4;
            *(float4*)&s_x[s][c * 4] =
                *(const float4*)(states + (size_t)(sbase + s) * SDIM + feat_off + c * 4);
        }
    }
    __syncthreads();

    // ---- stage 1: Psum (lane = h), 4 samples per wave ----
    {
        float w1r[DIN];
#pragma unroll
        for (int i = 0; i < DIN; ++i) w1r[i] = s_h1w[i * 64 + lane];
        const float b1r = s_h1b[lane];

        for (int ss = 0; ss < 4; ++ss) {
            const int s = wave * 4 + ss;
            float ps[DIN], xs[DIN];
#pragma unroll
            for (int i = 0; i < DIN; ++i) { ps[i] = 0.f; xs[i] = 0.f; }
#pragma unroll
            for (int a = 0; a < 8; ++a) {
                float x[DIN];
                if constexpr (DIN == 8) {
                    float4 v0 = *(const float4*)&s_x[s][a * 8];
                    float4 v1 = *(const float4*)&s_x[s][a * 8 + 4];
                    x[0] = v0.x; x[1] = v0.y; x[2] = v0.z; x[3] = v0.w;
                    x[4] = v1.x; x[5] = v1.y; x[6] = v1.z; x[7] = v1.w;
                } else {
                    float2 v0 = *(const float2*)&s_x[s][a * 6];
                    float2 v1 = *(const float2*)&s_x[s][a * 6 + 2];
                    float2 v2 = *(const float2*)&s_x[s][a * 6 + 4];
                    x[0] = v0.x; x[1] = v0.y; x[2] = v1.x; x[3] = v1.y; x[4] = v2.x; x[5] = v2.y;
                }
                float hacc = b1r;
#pragma unroll
                for (int i = 0; i < DIN; ++i) hacc += x[i] * w1r[i];
                hacc = fmaxf(hacc, 0.f);
#pragma unroll
                for (int i = 0; i < DIN; ++i) { ps[i] += hacc * x[i]; xs[i] += x[i]; }
            }
#pragma unroll
            for (int i = 0; i < DIN; ++i) s_psum[s * KP + i * 64 + lane] = (u16t)f2bf(ps[i]);
            if (lane == 0) {
#pragma unroll
                for (int i = 0; i < DIN; ++i) s_xsum[s][i] = xs[i];
            }
        }
    }
    __syncthreads();

    // ---- stage 2: MFMA. M=16 samples, wave = n-block (n0 = wave*16) ----
    const int lr = lane & 15, lg = lane >> 4;
    const int n0 = wave * 16;
    f32x4 acc = {0.f, 0.f, 0.f, 0.f};
    const u16t* arow = &s_psum[lr * KP + lg * 8];
    const bf16x8* wt8 = (const bf16x8*)wt;

#pragma unroll 4
    for (int kk = 0; kk < K; kk += 32) {
        bf16x8 av = *(const bf16x8*)(arow + kk);
        bf16x8 bv = wt8[((kk >> 3) + lg) * 64 + n0 + lr];
        acc = __builtin_amdgcn_mfma_f32_16x16x32_bf16(av, bv, acc, 0, 0, 0);
    }

    // ---- epilogue: D row=4*lg+j (sample), col=lr -> o = n0+lr ----
    const int o = n0 + lr;
#pragma unroll
    for (int j = 0; j < 4; ++j) {
        const int row = lg * 4 + j;
        float hb = 0.f;
#pragma unroll
        for (int i = 0; i < DIN; ++i) hb += s_xsum[row][i] * s_h2b[i * 64 + o];
        float res = (acc[j] + hb) * 0.125f + s_bias[o];
        emb[(size_t)(sbase + row) * 64 + o] = (u16t)f2bf(res);
    }
}

// ---------------------------------------------------------------------------
// C0: se + b1/w2/b2. 32 samples/block, grid 512.
// b1w2[s][0:32) = se@hb1_w + hb1_b ; [32:64) = |se@hw2_w + hw2_b| ; b2f[s].
// ---------------------------------------------------------------------------
__global__ __launch_bounds__(256, 2)
void se_kernel(const float* __restrict__ states,
               const u16t* __restrict__ embA, const u16t* __restrict__ embB,
               const float* __restrict__ act_w, const float* __restrict__ act_b,
               const float* __restrict__ hb1_w, const float* __restrict__ hb1_b,
               const float* __restrict__ hw2_w, const float* __restrict__ hw2_b,
               const float* __restrict__ hb2_w, const float* __restrict__ hb2_b,
               float* __restrict__ b1w2, float* __restrict__ b2f)
{
    __shared__ __align__(16) float s_act[32][112];
    __shared__ float s_am[32][14];
    __shared__ float s_w[64][64];      // [o][e<32: hb1_w | e>=32: hw2_w]
    __shared__ float s_actw[14 * 64];
    __shared__ float s_actb[64], s_hb2w[64], s_b1b[32], s_w2b[32];
    __shared__ float s_hb2b_s;
    __shared__ float s_se[32][64];

    const int tid = threadIdx.x;
    const int base = blockIdx.x * 32;

    for (int i = tid; i < 32 * 28; i += 256) {
        int s = i / 28, c = i - s * 28;
        *(float4*)&s_act[s][c * 4] = *(const float4*)(states + (size_t)(base + s) * SDIM + 112 + c * 4);
    }
    for (int i = tid; i < 2048; i += 256) {
        int o = i >> 5, e = i & 31;
        s_w[o][e]      = hb1_w[i];
        s_w[o][32 + e] = hw2_w[i];
    }
    for (int i = tid; i < 896; i += 256) s_actw[i] = act_w[i];
    if (tid < 64) { s_actb[tid] = act_b[tid]; s_hb2w[tid] = hb2_w[tid]; }
    else if (tid < 96)  s_b1b[tid - 64] = hb1_b[tid - 64];
    else if (tid < 128) s_w2b[tid - 96] = hw2_b[tid - 96];
    else if (tid == 128) s_hb2b_s = hb2_b[0];
    __syncthreads();

    for (int i = tid; i < 32 * 14; i += 256) {
        int s = i / 14, j = i - s * 14;
        float a = 0.f;
#pragma unroll
        for (int aa = 0; aa < 8; ++aa) a += s_act[s][aa * 14 + j];
        s_am[s][j] = a * 0.125f;
    }
    __syncthreads();

    const int wave = tid >> 6, lane = tid & 63;
    for (int ss = 0; ss < 8; ++ss) {
        const int s = wave * 8 + ss;
        const size_t gs = base + s;
        float se = s_actb[lane] + lo16((uint32_t)embA[gs * 64 + lane]) + lo16((uint32_t)embB[gs * 64 + lane]);
#pragma unroll
        for (int j = 0; j < 14; ++j) se += s_am[s][j] * s_actw[j * 64 + lane];
        se = fmaxf(se, 0.f);
        s_se[s][lane] = se;
        // b2 (wave reduce)
        float pb = se * s_hb2w[lane];
#pragma unroll
        for (int m2 = 1; m2 < 64; m2 <<= 1) pb += __shfl_xor(pb, m2);
        if (lane == 0) b2f[gs] = pb + s_hb2b_s;
        // b1 (lanes<32) / w2 (lanes>=32)  -- same-wave LDS RAW, compiler waits
        float v = (lane < 32) ? s_b1b[lane] : s_w2b[lane - 32];
#pragma unroll 8
        for (int o = 0; o < 64; ++o) v += s_se[s][o] * s_w[o][lane];
        if (lane >= 32) v = fabsf(v);
        b1w2[gs * 64 + lane] = v;
    }
}

// ---------------------------------------------------------------------------
// C2: z = hs @ hw1_w via MFMA, softmax over agents, q-mix, ELU, dot with w2.
// 16 samples/block (128 hs rows), grid 1024. hs staged bf16, stride 72 u16.
// ---------------------------------------------------------------------------
__global__ __launch_bounds__(256, 4)
void mix_kernel(const float* __restrict__ qvals, const float* __restrict__ hs,
                const float* __restrict__ hw1_w, const float* __restrict__ hw1_b,
                const float* __restrict__ b1w2, const float* __restrict__ b2f,
                float* __restrict__ out)
{
    __shared__ __align__(16) u16t s_hs[128 * 72];
    __shared__ __align__(16) u16t s_bt[32 * 72];   // hw1_w^T bf16 [e][k]
    __shared__ float s_q[128];
    __shared__ float s_w1b[32];

    const int tid = threadIdx.x;
    const size_t base = (size_t)blockIdx.x * 16;

    {
        const float4* hsv = (const float4*)(hs + base * 512);
        for (int i = tid; i < 2048; i += 256) {
            float4 v = hsv[i];
            int row = i >> 4, c4 = i & 15;
            uint2 p;
            p.x = f2bf(v.x) | (f2bf(v.y) << 16);
            p.y = f2bf(v.z) | (f2bf(v.w) << 16);
            *(uint2*)&s_hs[row * 72 + c4 * 4] = p;
        }
    }
    {
        const int e = tid & 31, k0 = (tid >> 5) * 8;
        uint32_t w[4];
#pragma unroll
        for (int jj = 0; jj < 4; ++jj) {
            uint32_t a = f2bf(hw1_w[(k0 + 2 * jj) * 32 + e]);
            uint32_t b = f2bf(hw1_w[(k0 + 2 * jj + 1) * 32 + e]);
            w[jj] = a | (b << 16);
        }
        *(uint4*)&s_bt[e * 72 + k0] = make_uint4(w[0], w[1], w[2], w[3]);
    }
    if (tid < 128) s_q[tid] = qvals[base * 8 + tid];
    if (tid < 32) s_w1b[tid] = hw1_b[tid];
    __syncthreads();

    const int wave = tid >> 6, lane = tid & 63, lr = lane & 15, lg = lane >> 4;

    bf16x8 bfr[2][2];
#pragma unroll
    for (int n = 0; n < 2; ++n)
#pragma unroll
        for (int ks = 0; ks < 2; ++ks)
            bfr[n][ks] = *(const bf16x8*)&s_bt[(n * 16 + lr) * 72 + ks * 32 + lg * 8];

    const float zb0 = s_w1b[lr], zb1 = s_w1b[16 + lr];

    for (int t = wave * 2; t < wave * 2 + 2; ++t) {
        f32x4 d0 = {0.f, 0.f, 0.f, 0.f}, d1 = {0.f, 0.f, 0.f, 0.f};
#pragma unroll
        for (int ks = 0; ks < 2; ++ks) {
            bf16x8 av = *(const bf16x8*)&s_hs[(t * 16 + lr) * 72 + ks * 32 + lg * 8];
            d0 = __builtin_amdgcn_mfma_f32_16x16x32_bf16(av, bfr[0][ks], d0, 0, 0, 0);
            d1 = __builtin_amdgcn_mfma_f32_16x16x32_bf16(av, bfr[1][ks], d1, 0, 0, 0);
        }
        const int sloc = t * 2 + (lg >> 1);
        const size_t gs = base + sloc;
        // z rows = agents 4*(lg&1)+j ; cols e = lr (d0) / 16+lr (d1)
        float z0[4], z1[4];
#pragma unroll
        for (int j = 0; j < 4; ++j) { z0[j] = d0[j] + zb0; z1[j] = d1[j] + zb1; }
        float m0 = fmaxf(fmaxf(z0[0], z0[1]), fmaxf(z0[2], z0[3]));
        float m1 = fmaxf(fmaxf(z1[0], z1[1]), fmaxf(z1[2], z1[3]));
        m0 = fmaxf(m0, __shfl_xor(m0, 16));
        m1 = fmaxf(m1, __shfl_xor(m1, 16));
        float qa[4];
        {
            float4 qv = *(const float4*)&s_q[sloc * 8 + (lg & 1) * 4];
            qa[0] = qv.x; qa[1] = qv.y; qa[2] = qv.z; qa[3] = qv.w;
        }
        float s0 = 0.f, s1 = 0.f, hp0 = 0.f, hp1 = 0.f;
#pragma unroll
        for (int j = 0; j < 4; ++j) {
            float e0 = __expf(z0[j] - m0), e1 = __expf(z1[j] - m1);
            s0 += e0; s1 += e1;
            hp0 += qa[j] * e0; hp1 += qa[j] * e1;
        }
        s0  += __shfl_xor(s0, 16);  s1  += __shfl_xor(s1, 16);
        hp0 += __shfl_xor(hp0, 16); hp1 += __shfl_xor(hp1, 16);

        const float b1_0 = b1w2[gs * 64 + lr],      b1_1 = b1w2[gs * 64 + 16 + lr];
        const float w2_0 = b1w2[gs * 64 + 32 + lr], w2_1 = b1w2[gs * 64 + 48 + lr];
        float h0 = hp0 / s0 + b1_0; h0 = (h0 > 0.f) ? h0 : (__expf(h0) - 1.f);
        float h1 = hp1 / s1 + b1_1; h1 = (h1 > 0.f) ? h1 : (__expf(h1) - 1.f);
        float yp = h0 * w2_0 + h1 * w2_1;
        yp += __shfl_xor(yp, 1); yp += __shfl_xor(yp, 2);
        yp += __shfl_xor(yp, 4); yp += __shfl_xor(yp, 8);
        if (lr == 0 && (lg & 1) == 0) out[gs] = yp + b2f[gs];
    }
}

extern "C" void kernel_launch(void* const* d_in, const int* in_sizes, int n_in,
                              void* d_out, int out_size, void* d_ws, size_t ws_size,
                              hipStream_t stream) {
    const float* qvals   = (const float*)d_in[0];
    const float* states  = (const float*)d_in[1];
    const float* hstates = (const float*)d_in[2];
    const float* hw1_w   = (const float*)d_in[3];
    const float* hw1_b   = (const float*)d_in[4];
    const float* en_h1w  = (const float*)d_in[5];
    const float* en_h1b  = (const float*)d_in[6];
    const float* en_h2w  = (const float*)d_in[7];
    const float* en_h2b  = (const float*)d_in[8];
    const float* en_bias = (const float*)d_in[9];
    const float* al_h1w  = (const float*)d_in[10];
    const float* al_h1b  = (const float*)d_in[11];
    const float* al_h2w  = (const float*)d_in[12];
    const float* al_h2b  = (const float*)d_in[13];
    const float* al_bias = (const float*)d_in[14];
    const float* act_w   = (const float*)d_in[15];
    const float* act_b   = (const float*)d_in[16];
    const float* hb1_w   = (const float*)d_in[17];
    const float* hb1_b   = (const float*)d_in[18];
    const float* hw2_w   = (const float*)d_in[19];
    const float* hw2_b   = (const float*)d_in[20];
    const float* hb2_w   = (const float*)d_in[21];
    const float* hb2_b   = (const float*)d_in[22];

    // ws (u16 units): wtA@0 | wtB@32768 | embA@65536 | embB@1114112 | b1w2(f32)@byte 4325376 | b2f
    u16t* wtA  = (u16t*)d_ws;
    u16t* wtB  = wtA + 32768;
    u16t* embA = wtA + 65536;
    u16t* embB = embA + 1048576;
    float* b1w2 = (float*)((char*)d_ws + 4325376);
    float* b2f  = b1w2 + 1048576;

    prep_wt_kernel<<<64, 256, 0, stream>>>(al_h2w, en_h2w, wtA, wtB);
    hyper_embed_mfma<8><<<1024, 256, 0, stream>>>(states, al_h1w, al_h1b, wtA, al_h2b, al_bias, embA, 0);
    hyper_embed_mfma<6><<<1024, 256, 0, stream>>>(states, en_h1w, en_h1b, wtB, en_h2b, en_bias, embB, 64);
    se_kernel<<<512, 256, 0, stream>>>(states, embA, embB, act_w, act_b,
                                       hb1_w, hb1_b, hw2_w, hw2_b, hb2_w, hb2_b, b1w2, b2f);
    mix_kernel<<<1024, 256, 0, stream>>>(qvals, hstates, hw1_w, hw1_b, b1w2, b2f, (float*)d_out);
}

// Round 8
// 41.408 us; speedup vs baseline: 3.6051x; 1.3113x over previous
//
#include <hip/hip_runtime.h>
#include <hip/hip_bf16.h>
#include <stdint.h>

typedef unsigned short u16t;
typedef float f32x4 __attribute__((ext_vector_type(4)));
typedef short bf16x8 __attribute__((ext_vector_type(8)));

#define SDIM 224

__device__ __forceinline__ float lo16(uint32_t w) { union { uint32_t u; float f; } v; v.u = w << 16; return v.f; }
__device__ __forceinline__ uint32_t f2bf(float f) {
    union { float f; uint32_t u; } v; v.f = f;
    return (v.u + 0x7FFFu + ((v.u >> 16) & 1u)) >> 16;
}

// ---------------------------------------------------------------------------
// Prep: pack all GEMM B-operands into MFMA-fragment order bf16.
// frag layout: buf[(kb*N + n)*8 + j] = bf16(W[kb*8+j][n])
//   wtA: W = al_h2w viewed as [k=i*64+h][n]  (K=512, N=64)
//   wtB: en_h2w same                          (K=384, N=64)
//   wt2: W[k][n<32]=hb1_w[k][n], W[k][n>=32]=hw2_w[k][n-32]   (K=64, N=64)
//   wtM: hw1_w [k][n]                          (K=64, N=32)
// ---------------------------------------------------------------------------
__global__ void prep_wt_kernel(const float* __restrict__ h2wA, const float* __restrict__ h2wB,
                               const float* __restrict__ hb1w, const float* __restrict__ hw2w,
                               const float* __restrict__ hw1w,
                               u16t* __restrict__ wtA, u16t* __restrict__ wtB,
                               u16t* __restrict__ wt2, u16t* __restrict__ wtM)
{
    const int t0 = blockIdx.x * 256 + threadIdx.x, stride = gridDim.x * 256;
    for (int e = t0; e < 32768; e += stride) {
        int j = e & 7, n = (e >> 3) & 63, kb = e >> 9;
        int k = kb * 8 + j, h = k & 63, i = k >> 6;
        wtA[e] = (u16t)f2bf(h2wA[h * 512 + i * 64 + n]);
    }
    for (int e = t0; e < 24576; e += stride) {
        int j = e & 7, n = (e >> 3) & 63, kb = e >> 9;
        int k = kb * 8 + j, h = k & 63, i = k >> 6;
        wtB[e] = (u16t)f2bf(h2wB[h * 384 + i * 64 + n]);
    }
    for (int e = t0; e < 4096; e += stride) {
        int j = e & 7, n = (e >> 3) & 63, kb = e >> 9;
        int k = kb * 8 + j;
        float v = (n < 32) ? hb1w[k * 32 + n] : hw2w[k * 32 + (n - 32)];
        wt2[e] = (u16t)f2bf(v);
    }
    for (int e = t0; e < 2048; e += stride) {
        int j = e & 7, n = (e >> 3) & 31, kb = e >> 8;
        int k = kb * 8 + j;
        wtM[e] = (u16t)f2bf(hw1w[k * 32 + n]);
    }
}

// ---------------------------------------------------------------------------
// Fully fused mixer: 16 samples/block, grid 1024, 256 threads.
// ---------------------------------------------------------------------------
template<int DIN>
__device__ __forceinline__ void stage1_psum(const float (*s_x)[SDIM], u16t* s_psum, int KP,
                                            const float* s_h1w, const float* s_h1b,
                                            float (*s_xsum)[8], int wave, int lane, int foff)
{
    float w1r[DIN];
#pragma unroll
    for (int i = 0; i < DIN; ++i) w1r[i] = s_h1w[i * 64 + lane];
    const float b1r = s_h1b[lane];
    for (int ss = 0; ss < 4; ++ss) {
        const int s = wave * 4 + ss;
        const float* xr = &s_x[s][foff];
        float ps[DIN], xs[DIN];
#pragma unroll
        for (int i = 0; i < DIN; ++i) { ps[i] = 0.f; xs[i] = 0.f; }
#pragma unroll
        for (int a = 0; a < 8; ++a) {
            float x[DIN];
            if constexpr (DIN == 8) {
                float4 v0 = *(const float4*)&xr[a * 8];
                float4 v1 = *(const float4*)&xr[a * 8 + 4];
                x[0] = v0.x; x[1] = v0.y; x[2] = v0.z; x[3] = v0.w;
                x[4] = v1.x; x[5] = v1.y; x[6] = v1.z; x[7] = v1.w;
            } else {
                float2 v0 = *(const float2*)&xr[a * 6];
                float2 v1 = *(const float2*)&xr[a * 6 + 2];
                float2 v2 = *(const float2*)&xr[a * 6 + 4];
                x[0] = v0.x; x[1] = v0.y; x[2] = v1.x; x[3] = v1.y; x[4] = v2.x; x[5] = v2.y;
            }
            float hacc = b1r;
#pragma unroll
            for (int i = 0; i < DIN; ++i) hacc += x[i] * w1r[i];
            hacc = fmaxf(hacc, 0.f);
#pragma unroll
            for (int i = 0; i < DIN; ++i) { ps[i] += hacc * x[i]; xs[i] += x[i]; }
        }
#pragma unroll
        for (int i = 0; i < DIN; ++i) s_psum[s * KP + i * 64 + lane] = (u16t)f2bf(ps[i]);
        if (lane == 0) {
#pragma unroll
            for (int i = 0; i < DIN; ++i) s_xsum[s][i] = xs[i];
        }
    }
}

__global__ __launch_bounds__(256, 2)
void fused_mixer(const float* __restrict__ qvals, const float* __restrict__ states,
                 const float* __restrict__ hs,
                 const float* __restrict__ al_h1w, const float* __restrict__ al_h1b,
                 const float* __restrict__ al_h2b, const float* __restrict__ al_bias,
                 const float* __restrict__ en_h1w, const float* __restrict__ en_h1b,
                 const float* __restrict__ en_h2b, const float* __restrict__ en_bias,
                 const float* __restrict__ act_w, const float* __restrict__ act_b,
                 const float* __restrict__ hb1_b, const float* __restrict__ hw2_b,
                 const float* __restrict__ hw1_b, const float* __restrict__ hb2_w,
                 const float* __restrict__ hb2_b,
                 const u16t* __restrict__ wtA, const u16t* __restrict__ wtB,
                 const u16t* __restrict__ wt2, const u16t* __restrict__ wtM,
                 float* __restrict__ out)
{
    __shared__ __align__(16) float s_x[16][SDIM];          // 14336 B
    __shared__ __align__(16) char  s_union[128 * 72 * 2];  // 18432 B: psumA/psumB then hs
    __shared__ __align__(16) u16t  s_se[16 * 72];          // 2304 B (bf16 A-frag layout)
    __shared__ float s_b1w2[16][64];                       // 4096 B
    __shared__ float s_b2[16];
    __shared__ float s_q[128];
    __shared__ float s_am[16][14];
    __shared__ float s_xsum[16][8];
    __shared__ float s_h1wA[512], s_h2bA[512];
    __shared__ float s_h1wB[384], s_h2bB[384];
    __shared__ float s_actw[896];
    __shared__ float s_h1bA[64], s_h1bB[64], s_biasA[64], s_biasB[64], s_actb[64], s_hb2w[64];
    __shared__ float s_b1b[32], s_w2b[32], s_w1b[32];
    __shared__ float s_hb2b;

    const int tid  = threadIdx.x;
    const int wave = tid >> 6;
    const int lane = tid & 63;
    const int lr = lane & 15, lg = lane >> 4;
    const int sbase = blockIdx.x * 16;

    // ---- early: issue hs loads into registers (consumed after phase B) ----
    float4 hsr[8];
    {
        const float4* hsv = (const float4*)(hs + (size_t)sbase * 512);
#pragma unroll
        for (int i = 0; i < 8; ++i) hsr[i] = hsv[i * 256 + tid];
    }
    if (tid < 128) s_q[tid] = qvals[(size_t)sbase * 8 + tid];

    // ---- cooperative staging ----
    for (int i = tid; i < 16 * 56; i += 256) {
        int s = i / 56, c = i - s * 56;
        *(float4*)&s_x[s][c * 4] = *(const float4*)(states + (size_t)(sbase + s) * SDIM + c * 4);
    }
    for (int i = tid; i < 512; i += 256) { s_h1wA[i] = al_h1w[i]; s_h2bA[i] = al_h2b[i]; }
    for (int i = tid; i < 384; i += 256) { s_h1wB[i] = en_h1w[i]; s_h2bB[i] = en_h2b[i]; }
    for (int i = tid; i < 896; i += 256) s_actw[i] = act_w[i];
    if (tid < 64) {
        s_h1bA[tid] = al_h1b[tid]; s_h1bB[tid] = en_h1b[tid];
        s_biasA[tid] = al_bias[tid]; s_biasB[tid] = en_bias[tid];
        s_actb[tid] = act_b[tid]; s_hb2w[tid] = hb2_w[tid];
    }
    if (tid >= 64 && tid < 96)  s_b1b[tid - 64] = hb1_b[tid - 64];
    if (tid >= 96 && tid < 128) s_w2b[tid - 96] = hw2_b[tid - 96];
    if (tid >= 128 && tid < 160) s_w1b[tid - 128] = hw1_b[tid - 128];
    if (tid == 160) s_hb2b = hb2_b[0];
    __syncthreads();                                   // B0

    u16t* s_psum = (u16t*)s_union;
    constexpr int KPA = 520, KPB = 392;

    // ---- phase A stage1 + action means ----
    stage1_psum<8>(s_x, s_psum, KPA, s_h1wA, s_h1bA, s_xsum, wave, lane, 0);
    for (int i = tid; i < 224; i += 256) {
        int s = i / 14, j = i - s * 14;
        float a = 0.f;
#pragma unroll
        for (int aa = 0; aa < 8; ++aa) a += s_x[s][112 + aa * 14 + j];
        s_am[s][j] = a * 0.125f;
    }
    __syncthreads();                                   // B1

    // ---- phase A MFMA (M=16, N=64 split across waves, K=512) ----
    const int n0 = wave * 16;
    const int o  = n0 + lr;
    float e[4];
    {
        f32x4 acc = {0.f, 0.f, 0.f, 0.f};
        const u16t* arow = &s_psum[lr * KPA + lg * 8];
        const bf16x8* wt8 = (const bf16x8*)wtA;
#pragma unroll 4
        for (int kk = 0; kk < 512; kk += 32) {
            bf16x8 av = *(const bf16x8*)(arow + kk);
            bf16x8 bv = wt8[((kk >> 3) + lg) * 64 + o];
            acc = __builtin_amdgcn_mfma_f32_16x16x32_bf16(av, bv, acc, 0, 0, 0);
        }
#pragma unroll
        for (int j = 0; j < 4; ++j) {
            const int row = lg * 4 + j;
            float hb = 0.f;
#pragma unroll
            for (int i = 0; i < 8; ++i) hb += s_xsum[row][i] * s_h2bA[i * 64 + o];
            e[j] = (acc[j] + hb) * 0.125f + s_biasA[o];
        }
    }
    __syncthreads();                                   // B2 (psum free, xsum consumed)

    // ---- phase B stage1 ----
    stage1_psum<6>(s_x, s_psum, KPB, s_h1wB, s_h1bB, s_xsum, wave, lane, 64);
    __syncthreads();                                   // B3

    // ---- phase B MFMA + se epilogue ----
    {
        f32x4 acc = {0.f, 0.f, 0.f, 0.f};
        const u16t* arow = &s_psum[lr * KPB + lg * 8];
        const bf16x8* wt8 = (const bf16x8*)wtB;
#pragma unroll 4
        for (int kk = 0; kk < 384; kk += 32) {
            bf16x8 av = *(const bf16x8*)(arow + kk);
            bf16x8 bv = wt8[((kk >> 3) + lg) * 64 + o];
            acc = __builtin_amdgcn_mfma_f32_16x16x32_bf16(av, bv, acc, 0, 0, 0);
        }
#pragma unroll
        for (int j = 0; j < 4; ++j) {
            const int row = lg * 4 + j;
            float hb = 0.f;
#pragma unroll
            for (int i = 0; i < 6; ++i) hb += s_xsum[row][i] * s_h2bB[i * 64 + o];
            float se = e[j] + (acc[j] + hb) * 0.125f + s_biasB[o] + s_actb[o];
#pragma unroll
            for (int j2 = 0; j2 < 14; ++j2) se += s_am[row][j2] * s_actw[j2 * 64 + o];
            se = fmaxf(se, 0.f);
            s_se[row * 72 + o] = (u16t)f2bf(se);
        }
    }
    __syncthreads();                                   // B4 (se ready, psum region free)

    // ---- region: hs regs -> LDS  |  b1w2 MFMA  |  b2 reduce ----
    u16t* s_hs = (u16t*)s_union;
    {
#pragma unroll
        for (int i = 0; i < 8; ++i) {
            const int idx = i * 256 + tid;
            const int row = idx >> 4, c4 = idx & 15;
            uint2 p;
            p.x = f2bf(hsr[i].x) | (f2bf(hsr[i].y) << 16);
            p.y = f2bf(hsr[i].z) | (f2bf(hsr[i].w) << 16);
            *(uint2*)&s_hs[row * 72 + c4 * 4] = p;
        }
    }
    {   // b1w2: M=16 (samples), K=64 (se), N=64 (b1|w2)
        f32x4 acc = {0.f, 0.f, 0.f, 0.f};
        const bf16x8* wt8 = (const bf16x8*)wt2;
#pragma unroll
        for (int ks = 0; ks < 2; ++ks) {
            bf16x8 av = *(const bf16x8*)&s_se[lr * 72 + ks * 32 + lg * 8];
            bf16x8 bv = wt8[(ks * 4 + lg) * 64 + o];
            acc = __builtin_amdgcn_mfma_f32_16x16x32_bf16(av, bv, acc, 0, 0, 0);
        }
#pragma unroll
        for (int j = 0; j < 4; ++j) {
            const int row = lg * 4 + j;
            float v = acc[j] + ((o < 32) ? s_b1b[o] : s_w2b[o - 32]);
            if (o >= 32) v = fabsf(v);
            s_b1w2[row][o] = v;
        }
    }
    {   // b2: wave handles 4 samples, 16-lane groups reduce over o
        const int smp = wave * 4 + lg;
        float p = 0.f;
#pragma unroll
        for (int c = 0; c < 4; ++c) {
            const int oo = c * 16 + lr;
            p += lo16((uint32_t)s_se[smp * 72 + oo]) * s_hb2w[oo];
        }
        p += __shfl_xor(p, 1); p += __shfl_xor(p, 2);
        p += __shfl_xor(p, 4); p += __shfl_xor(p, 8);
        if (lr == 0) s_b2[smp] = p + s_hb2b;
    }
    __syncthreads();                                   // B5

    // ---- mix: z MFMA, softmax over 8 agents, q-mix, ELU, dot w2 ----
    bf16x8 bfr[2][2];
    {
        const bf16x8* wtm8 = (const bf16x8*)wtM;
#pragma unroll
        for (int n = 0; n < 2; ++n)
#pragma unroll
            for (int ks = 0; ks < 2; ++ks)
                bfr[n][ks] = wtm8[(ks * 4 + lg) * 32 + n * 16 + lr];
    }
    const float zb0 = s_w1b[lr], zb1 = s_w1b[16 + lr];

    for (int t = wave * 2; t < wave * 2 + 2; ++t) {
        f32x4 d0 = {0.f, 0.f, 0.f, 0.f}, d1 = {0.f, 0.f, 0.f, 0.f};
#pragma unroll
        for (int ks = 0; ks < 2; ++ks) {
            bf16x8 av = *(const bf16x8*)&s_hs[(t * 16 + lr) * 72 + ks * 32 + lg * 8];
            d0 = __builtin_amdgcn_mfma_f32_16x16x32_bf16(av, bfr[0][ks], d0, 0, 0, 0);
            d1 = __builtin_amdgcn_mfma_f32_16x16x32_bf16(av, bfr[1][ks], d1, 0, 0, 0);
        }
        const int sloc = t * 2 + (lg >> 1);
        float z0[4], z1[4];
#pragma unroll
        for (int j = 0; j < 4; ++j) { z0[j] = d0[j] + zb0; z1[j] = d1[j] + zb1; }
        float m0 = fmaxf(fmaxf(z0[0], z0[1]), fmaxf(z0[2], z0[3]));
        float m1 = fmaxf(fmaxf(z1[0], z1[1]), fmaxf(z1[2], z1[3]));
        m0 = fmaxf(m0, __shfl_xor(m0, 16));
        m1 = fmaxf(m1, __shfl_xor(m1, 16));
        float qa[4];
        {
            float4 qv = *(const float4*)&s_q[sloc * 8 + (lg & 1) * 4];
            qa[0] = qv.x; qa[1] = qv.y; qa[2] = qv.z; qa[3] = qv.w;
        }
        float s0 = 0.f, s1 = 0.f, hp0 = 0.f, hp1 = 0.f;
#pragma unroll
        for (int j = 0; j < 4; ++j) {
            float e0 = __expf(z0[j] - m0), e1 = __expf(z1[j] - m1);
            s0 += e0; s1 += e1;
            hp0 += qa[j] * e0; hp1 += qa[j] * e1;
        }
        s0  += __shfl_xor(s0, 16);  s1  += __shfl_xor(s1, 16);
        hp0 += __shfl_xor(hp0, 16); hp1 += __shfl_xor(hp1, 16);

        const float b1_0 = s_b1w2[sloc][lr],      b1_1 = s_b1w2[sloc][16 + lr];
        const float w2_0 = s_b1w2[sloc][32 + lr], w2_1 = s_b1w2[sloc][48 + lr];
        float h0 = hp0 / s0 + b1_0; h0 = (h0 > 0.f) ? h0 : (__expf(h0) - 1.f);
        float h1 = hp1 / s1 + b1_1; h1 = (h1 > 0.f) ? h1 : (__expf(h1) - 1.f);
        float yp = h0 * w2_0 + h1 * w2_1;
        yp += __shfl_xor(yp, 1); yp += __shfl_xor(yp, 2);
        yp += __shfl_xor(yp, 4); yp += __shfl_xor(yp, 8);
        if (lr == 0 && (lg & 1) == 0) out[sbase + sloc] = yp + s_b2[sloc];
    }
}

extern "C" void kernel_launch(void* const* d_in, const int* in_sizes, int n_in,
                              void* d_out, int out_size, void* d_ws, size_t ws_size,
                              hipStream_t stream) {
    const float* qvals   = (const float*)d_in[0];
    const float* states  = (const float*)d_in[1];
    const float* hstates = (const float*)d_in[2];
    const float* hw1_w   = (const float*)d_in[3];
    const float* hw1_b   = (const float*)d_in[4];
    const float* en_h1w  = (const float*)d_in[5];
    const float* en_h1b  = (const float*)d_in[6];
    const float* en_h2w  = (const float*)d_in[7];
    const float* en_h2b  = (const float*)d_in[8];
    const float* en_bias = (const float*)d_in[9];
    const float* al_h1w  = (const float*)d_in[10];
    const float* al_h1b  = (const float*)d_in[11];
    const float* al_h2w  = (const float*)d_in[12];
    const float* al_h2b  = (const float*)d_in[13];
    const float* al_bias = (const float*)d_in[14];
    const float* act_w   = (const float*)d_in[15];
    const float* act_b   = (const float*)d_in[16];
    const float* hb1_w   = (const float*)d_in[17];
    const float* hb1_b   = (const float*)d_in[18];
    const float* hw2_w   = (const float*)d_in[19];
    const float* hw2_b   = (const float*)d_in[20];
    const float* hb2_w   = (const float*)d_in[21];
    const float* hb2_b   = (const float*)d_in[22];

    // ws (u16 units): wtA@0 (32768) | wtB@32768 (24576) | wt2@57344 (4096) | wtM@61440 (2048)
    u16t* wtA = (u16t*)d_ws;
    u16t* wtB = wtA + 32768;
    u16t* wt2 = wtA + 57344;
    u16t* wtM = wtA + 61440;

    prep_wt_kernel<<<64, 256, 0, stream>>>(al_h2w, en_h2w, hb1_w, hw2_w, hw1_w, wtA, wtB, wt2, wtM);
    fused_mixer<<<1024, 256, 0, stream>>>(qvals, states, hstates,
                                          al_h1w, al_h1b, al_h2b, al_bias,
                                          en_h1w, en_h1b, en_h2b, en_bias,
                                          act_w, act_b, hb1_b, hw2_b, hw1_b, hb2_w, hb2_b,
                                          wtA, wtB, wt2, wtM, (float*)d_out);
}